// Round 2
// baseline (267.863 us; speedup 1.0000x reference)
//
#include <hip/hip_runtime.h>
#include <hip/hip_bf16.h>
#include <stdint.h>

#define T_SEQ 2048
#define DMODEL 1024
#define NH 16
#define DKH 64
#define M_TOK 8192   // B*T
#define N_QKV 3072
#define K_DIM 1024

#define ATTN_SC (0.125f * 1.44269504f)  // 1/sqrt(64) * log2(e), folded into Q store

typedef __attribute__((ext_vector_type(8))) short short8;
typedef __attribute__((ext_vector_type(4))) short short4v;
typedef __attribute__((ext_vector_type(4))) float float4v;
typedef __attribute__((ext_vector_type(2))) unsigned int uint2v;

__device__ inline short bf16_bits(float f) {
  __hip_bfloat16 h = __float2bfloat16(f);
  short s;
  __builtin_memcpy(&s, &h, 2);
  return s;
}

// fast f32x4 -> bf16x4: round-half-up via +0x8000 then take hi16
__device__ inline short4v pack4_bf16_fast(float a, float b, float c, float d) {
  unsigned ua = __builtin_bit_cast(unsigned, a) + 0x8000u;
  unsigned ub = __builtin_bit_cast(unsigned, b) + 0x8000u;
  unsigned uc = __builtin_bit_cast(unsigned, c) + 0x8000u;
  unsigned ud = __builtin_bit_cast(unsigned, d) + 0x8000u;
  uint2v uu = {(ua >> 16) | (ub & 0xFFFF0000u),
               (uc >> 16) | (ud & 0xFFFF0000u)};
  return __builtin_bit_cast(short4v, uu);
}

__device__ inline void async_load16(const void* g, void* l) {
  __builtin_amdgcn_global_load_lds(
      (const __attribute__((address_space(1))) unsigned int*)g,
      (__attribute__((address_space(3))) unsigned int*)l,
      16, 0, 0);
}

// ---------------- preprocessing ----------------

__global__ __launch_bounds__(256) void cvt_kernel(const float* __restrict__ in,
                                                  short* __restrict__ out, int n) {
  int idx = (blockIdx.x * 256 + threadIdx.x) * 4;
  if (idx < n) {
    float4v v = *(const float4v*)(in + idx);
    short4v o;
    o[0] = bf16_bits(v[0]); o[1] = bf16_bits(v[1]);
    o[2] = bf16_bits(v[2]); o[3] = bf16_bits(v[3]);
    *(short4v*)(out + idx) = o;
  }
}

// in: [K][N] fp32 row-major  ->  out: [N][K] bf16 row-major
__global__ __launch_bounds__(256) void transpose_cvt(const float* __restrict__ in,
                                                     short* __restrict__ out,
                                                     int K, int N) {
  __shared__ float tile[32][33];
  int n0 = blockIdx.x * 32, k0 = blockIdx.y * 32;
  int tx = threadIdx.x, ty = threadIdx.y;  // (32,8)
  #pragma unroll
  for (int r = ty; r < 32; r += 8)
    tile[r][tx] = in[(size_t)(k0 + r) * N + n0 + tx];
  __syncthreads();
  #pragma unroll
  for (int r = ty; r < 32; r += 8)
    out[(size_t)(n0 + r) * K + k0 + tx] = bf16_bits(tile[tx][r]);
}

// ---------------- double-buffered GEMM: C[M,N] = A[M,K] * Bt[N,K]^T + bias ----
// LDS chunk-rotation swizzle: 16-B chunk c of row r lives at slot (c+(r>>1))&3
// -> every b128 frag-read quarter-phase hits 2 words/bank (conflict-free).
// Staging stays a linear DMA; the lane's GLOBAL chunk offset is permuted.
// EPI 0: Q+K scatter, C^T orientation (lane holds 4 consecutive dk) -> vec stores
//   Qb [B*H, T, 64]  (row-major, PRE-SCALED by ATTN_SC)
//   Kf [B*H, kb64, c(4), h(2), quad(4), l16(16), w(8)]    (fragment-major)
// EPI 1: V scatter, normal orientation (lane holds 4 consecutive tokens)
//   Vf [B*H, kb64, c(4), d(4), quad(4), l16(16), kk(4)]   (fragment-major)
// EPI 2: fp32 C^T epilogue -> Cout [M,N] via float4
// Grid: x = M-tile -> XCD = m%8 (per-XCD L2 keeps the A-stripe hot).

template <int EPI>
__global__ __launch_bounds__(256) void gemm_bt(
    const short* __restrict__ A, const short* __restrict__ Bt,
    const float* __restrict__ bias,
    short* __restrict__ Qb, short* __restrict__ Kf, short* __restrict__ Vf,
    float* __restrict__ Cout, int M, int N, int K, int ntile0) {
  constexpr bool CT = (EPI != 1);
  __shared__ __align__(16) short AsB[2][128 * 32];
  __shared__ __align__(16) short BsB[2][128 * 32];
  const int tid = threadIdx.x;
  const int lane = tid & 63;
  const int wave = tid >> 6;
  const int m0 = blockIdx.x * 128;
  const int n0 = (blockIdx.y + ntile0) * 128;
  const int wm = (wave >> 1) * 64;
  const int wn = (wave & 1) * 64;
  const int quad = lane >> 4;
  const int l16 = lane & 15;

  float4v acc[4][4] = {};

  // staging: lane covers LDS chunk p=tid (and p=tid+256); row=p>>2, slot=p&3;
  // global chunk c = (slot - (row>>1)) & 3  (lane-constant swizzle offset)
  const int r0 = tid >> 2, r1 = r0 + 64;
  const int oswz = (((tid & 3) - (tid >> 3)) & 3) * 8;
  const int lo0 = wave * 512;
  const int lo1 = 2048 + wave * 512;

  const short* Ag0 = A  + (size_t)(m0 + r0) * K + oswz;
  const short* Ag1 = A  + (size_t)(m0 + r1) * K + oswz;
  const short* Bg0 = Bt + (size_t)(n0 + r0) * K + oswz;
  const short* Bg1 = Bt + (size_t)(n0 + r1) * K + oswz;

  // frag-read swizzle offset (lane-constant): slot = (quad + (row>>1)) & 3
  const int sw = ((quad + (l16 >> 1)) & 3) * 8;

  // prologue: stage K-tile 0 into buffer 0
  async_load16(Ag0, &AsB[0][0] + lo0);
  async_load16(Ag1, &AsB[0][0] + lo1);
  async_load16(Bg0, &BsB[0][0] + lo0);
  async_load16(Bg1, &BsB[0][0] + lo1);

  const int nkt = K >> 5;
  for (int it = 0; it < nkt; ++it) {
    __builtin_amdgcn_s_waitcnt(0);   // this tile's DMA complete
    __syncthreads();                 // visible to all; prev buffer free

    if (it + 1 < nkt) {              // prefetch next K-tile into other buffer
      const int kt = (it + 1) << 5;
      const int nb = (it + 1) & 1;
      async_load16(Ag0 + kt, &AsB[nb][0] + lo0);
      async_load16(Ag1 + kt, &AsB[nb][0] + lo1);
      async_load16(Bg0 + kt, &BsB[nb][0] + lo0);
      async_load16(Bg1 + kt, &BsB[nb][0] + lo1);
    }

    const short* As = &AsB[it & 1][0];
    const short* Bs = &BsB[it & 1][0];
    short8 af[4], bfr[4];
    #pragma unroll
    for (int t = 0; t < 4; ++t)
      af[t] = *(const short8*)(As + (size_t)(wm + t * 16 + l16) * 32 + sw);
    #pragma unroll
    for (int t = 0; t < 4; ++t)
      bfr[t] = *(const short8*)(Bs + (size_t)(wn + t * 16 + l16) * 32 + sw);
    #pragma unroll
    for (int i = 0; i < 4; ++i)
      #pragma unroll
      for (int j = 0; j < 4; ++j) {
        if (CT)
          acc[i][j] = __builtin_amdgcn_mfma_f32_16x16x32_bf16(bfr[j], af[i], acc[i][j], 0, 0, 0);
        else
          acc[i][j] = __builtin_amdgcn_mfma_f32_16x16x32_bf16(af[i], bfr[j], acc[i][j], 0, 0, 0);
      }
  }

  if (EPI == 0) {
    // C^T: reg i = col (dk) colb+i, lane l16 = token
    const int which = n0 >> 10;      // 0:q 1:k (uniform per block)
    #pragma unroll
    for (int tj = 0; tj < 4; ++tj) {
      const int colb = n0 + wn + tj * 16 + quad * 4;   // 4 consecutive cols
      float4v bz = *(const float4v*)(bias + colb);
      const int d = colb & 1023;
      const int h = d >> 6, dkb = d & 63;
      #pragma unroll
      for (int ti = 0; ti < 4; ++ti) {
        const int tok = m0 + wm + ti * 16 + l16;
        const int b = tok >> 11, t = tok & 2047;
        const size_t bhoff = (size_t)(b * NH + h) * (T_SEQ * DKH);
        float4v v = acc[ti][tj];
        if (which == 0) {
          short4v o = pack4_bf16_fast((v[0] + bz[0]) * ATTN_SC, (v[1] + bz[1]) * ATTN_SC,
                                      (v[2] + bz[2]) * ATTN_SC, (v[3] + bz[3]) * ATTN_SC);
          *(short4v*)(Qb + bhoff + (size_t)t * DKH + dkb) = o;
        } else {
          short4v o = pack4_bf16_fast(v[0] + bz[0], v[1] + bz[1], v[2] + bz[2], v[3] + bz[3]);
          const int h2 = dkb >> 5, qd = (dkb >> 3) & 3, w = dkb & 7;
          size_t kbase = bhoff + (size_t)(t >> 6) * 4096 +
                         ((((t >> 4) & 3) * 2 + h2) * 4 + qd) * 128 + (t & 15) * 8 + w;
          *(short4v*)(Kf + kbase) = o;
        }
      }
    }
  } else if (EPI == 1) {
    // normal C: reg i = token rbase+i, lane l16 = col
    #pragma unroll
    for (int tj = 0; tj < 4; ++tj) {
      const int col = n0 + wn + tj * 16 + l16;
      const float bz = bias[col];
      const int d = col & 1023;
      const int h = d >> 6, dk = d & 63;
      #pragma unroll
      for (int ti = 0; ti < 4; ++ti) {
        const int rbase = m0 + wm + ti * 16 + quad * 4;
        const int b = rbase >> 11, t = rbase & 2047;
        const size_t bhoff = (size_t)(b * NH + h) * (T_SEQ * DKH);
        float4v v = acc[ti][tj];
        short4v pv = pack4_bf16_fast(v[0] + bz, v[1] + bz, v[2] + bz, v[3] + bz);
        size_t off = bhoff + (size_t)(t >> 6) * 4096 +
                     ((((t >> 4) & 3) * 4 + (dk >> 4)) * 4 + ((t >> 2) & 3)) * 64 +
                     (dk & 15) * 4;
        *(short4v*)(Vf + off) = pv;
      }
    }
  } else {
    // C^T fp32: float4 along cols, lane l16 = row
    #pragma unroll
    for (int tj = 0; tj < 4; ++tj) {
      const int colb = n0 + wn + tj * 16 + quad * 4;
      float4v bz = *(const float4v*)(bias + colb);
      #pragma unroll
      for (int ti = 0; ti < 4; ++ti) {
        const int row = m0 + wm + ti * 16 + l16;
        float4v v = acc[ti][tj];
        float4v o = {v[0] + bz[0], v[1] + bz[1], v[2] + bz[2], v[3] + bz[3]};
        *(float4v*)(Cout + (size_t)row * N + colb) = o;
      }
    }
  }
}

// ---------------- flash attention (S^T, max-free, register PV, frag-major KV) --
// Block = 4 waves = 256 q rows of one (b,h); wave = 64 q rows (qi=0..3).
// S^T = K·Q^T (C: row=key=quad*4+i, col=q=l16); P stays in registers as the
// B-frag of mfma_16x16x16bf16_1k; O^T += V^T·P; l via ones-row MFMA.
// exp2 via raw v_exp_f32; P bf16 via round-half-up truncation (proven path).
// With 64-row waves, the diagonal tile always has dkq==0: sub-tiles qi<c are
// fully masked (skipped); qi==c masks with quad*4+i-l16>0; qi>c unmasked.

template <int MASK>
__device__ __forceinline__ void attn_tile(
    const short* __restrict__ Ks, const short* __restrict__ Vs,
    const short8 aq[4][2], short4v ones,
    float4v oc[4][4], float4v lc[4],
    int quad, int l16) {
  #pragma unroll
  for (int c = 0; c < 4; ++c) {
    short8 b0 = *(const short8*)(Ks + (c * 2 + 0) * 512 + quad * 128 + l16 * 8);
    short8 b1 = *(const short8*)(Ks + (c * 2 + 1) * 512 + quad * 128 + l16 * 8);
    short4v vf[4];
    #pragma unroll
    for (int d = 0; d < 4; ++d)
      vf[d] = *(const short4v*)(Vs + (c * 4 + d) * 256 + quad * 64 + l16 * 4);
    #pragma unroll
    for (int qi = 0; qi < 4; ++qi) {
      if (MASK && qi < c) continue;          // fully above diagonal sub-tile
      float4v z = {0.f, 0.f, 0.f, 0.f};
      z = __builtin_amdgcn_mfma_f32_16x16x32_bf16(b0, aq[qi][0], z, 0, 0, 0);
      z = __builtin_amdgcn_mfma_f32_16x16x32_bf16(b1, aq[qi][1], z, 0, 0, 0);
      float p[4];
      #pragma unroll
      for (int i = 0; i < 4; ++i) {
        p[i] = __builtin_amdgcn_exp2f(z[i]);   // Q pre-scaled by 1/sqrt(dk)*log2e
        if (MASK && qi == c && (quad * 4 + i - l16 > 0)) p[i] = 0.f;
      }
      short4v pb = pack4_bf16_fast(p[0], p[1], p[2], p[3]);
      lc[qi] = __builtin_amdgcn_mfma_f32_16x16x16bf16_1k(ones, pb, lc[qi], 0, 0, 0);
      #pragma unroll
      for (int d = 0; d < 4; ++d)
        oc[qi][d] = __builtin_amdgcn_mfma_f32_16x16x16bf16_1k(vf[d], pb, oc[qi][d], 0, 0, 0);
    }
  }
}

__global__ __launch_bounds__(256) void attn_kernel(const short* __restrict__ Qb,
                                                   const short* __restrict__ Kf,
                                                   const short* __restrict__ Vf,
                                                   short* __restrict__ Ao) {
  __shared__ __align__(16) short KsB[2][4096];   // 2 x 8 KB
  __shared__ __align__(16) short VsB[2][4096];   // 2 x 8 KB
  const int bh = blockIdx.x;                 // 0..63 -> XCD = bh&7 (balance + L2 pin)
  const int y = blockIdx.y;                  // 0..7
  // longest-first AND per-CU pairing: co-resident blocks y and y+4 sum to a
  // constant 36 tile-iterations -> flat per-CU work instead of 24..48.
  const int qblk = (y < 4) ? (7 - y) : (y - 4);
  const int tid = threadIdx.x;
  const int lane = tid & 63, wave = tid >> 6;
  const int quad = lane >> 4, l16 = lane & 15;
  const int qw0 = qblk * 256 + wave * 64;    // this wave's first q row
  const int nkb = 4 * qblk + 4;              // block-level tile count
  const int myk = 4 * qblk + wave;           // this wave's diagonal tile index

  const short* Qg = Qb + ((size_t)bh * T_SEQ + qw0) * DKH;
  const short* Kg0 = Kf + (size_t)bh * (T_SEQ * DKH);
  const short* Vg0 = Vf + (size_t)bh * (T_SEQ * DKH);

  // Q fragments (B-operand of S^T mfma): [q=qi*16+l16][k dim=h*32+quad*8]
  short8 aq[4][2];
  #pragma unroll
  for (int qi = 0; qi < 4; ++qi)
    #pragma unroll
    for (int h = 0; h < 2; ++h)
      aq[qi][h] = *(const short8*)(Qg + (size_t)(qi * 16 + l16) * DKH + h * 32 + quad * 8);

  float4v oc[4][4] = {};     // O^T: row d = quad*4+i (+16*dblk), col q = l16
  float4v lc[4] = {};        // ones-row MFMA accumulators: every reg = l(q=l16)
  short4v ones = {0x3F80, 0x3F80, 0x3F80, 0x3F80};   // bf16 1.0 x4

  // stage tile 0 into buffer 0 (linear 8KB copies)
  async_load16(Kg0 + tid * 8,        &KsB[0][0] + wave * 512);
  async_load16(Kg0 + 2048 + tid * 8, &KsB[0][0] + 2048 + wave * 512);
  async_load16(Vg0 + tid * 8,        &VsB[0][0] + wave * 512);
  async_load16(Vg0 + 2048 + tid * 8, &VsB[0][0] + 2048 + wave * 512);

  for (int kb = 0; kb < nkb; ++kb) {
    __builtin_amdgcn_s_waitcnt(0);   // drain this tile's DMA
    __syncthreads();

    if (kb + 1 < nkb) {              // prefetch next tile into other buffer
      const int nb = (kb + 1) & 1;
      const short* Kg = Kg0 + (size_t)(kb + 1) * 4096;
      const short* Vg = Vg0 + (size_t)(kb + 1) * 4096;
      async_load16(Kg + tid * 8,        &KsB[nb][0] + wave * 512);
      async_load16(Kg + 2048 + tid * 8, &KsB[nb][0] + 2048 + wave * 512);
      async_load16(Vg + tid * 8,        &VsB[nb][0] + wave * 512);
      async_load16(Vg + 2048 + tid * 8, &VsB[nb][0] + 2048 + wave * 512);
    }

    if (kb < myk) {                  // fully-causal tile: no mask ops
      attn_tile<0>(&KsB[kb & 1][0], &VsB[kb & 1][0], aq, ones, oc, lc, quad, l16);
    } else if (kb == myk) {          // diagonal tile (dkq==0 exactly)
      attn_tile<1>(&KsB[kb & 1][0], &VsB[kb & 1][0], aq, ones, oc, lc, quad, l16);
    }                                // else: fully above diagonal -> idle (stage only)
  }

  const int b = bh >> 4, h = bh & 15;
  #pragma unroll
  for (int qi = 0; qi < 4; ++qi) {
    float rl = 1.0f / lc[qi][0];     // every reg/lane of lc = row-sum l(q=l16)
    #pragma unroll
    for (int d = 0; d < 4; ++d) {
      short4v o;
      #pragma unroll
      for (int i = 0; i < 4; ++i) o[i] = bf16_bits(oc[qi][d][i] * rl);
      int t = qw0 + qi * 16 + l16;
      *(short4v*)(Ao + (size_t)(b * T_SEQ + t) * DMODEL + h * DKH + d * 16 + quad * 4) = o;
    }
  }
}

// ---------------- launch ----------------

extern "C" void kernel_launch(void* const* d_in, const int* in_sizes, int n_in,
                              void* d_out, int out_size, void* d_ws, size_t ws_size,
                              hipStream_t stream) {
  const float* x    = (const float*)d_in[0];
  const float* Wqkv = (const float*)d_in[1];
  const float* bqkv = (const float*)d_in[2];
  const float* Wout = (const float*)d_in[3];
  const float* bout = (const float*)d_in[4];
  float* out = (float*)d_out;

  char* ws = (char*)d_ws;
  short* Xb    = (short*)(ws);                          // 16 MB  [8192,1024] bf16
  short* Wqkvt = (short*)(ws + (16ull << 20));          //  6 MB  [3072,1024] bf16
  short* Woutt = (short*)(ws + (22ull << 20));          //  2 MB  [1024,1024] bf16
  short* Qb    = (short*)(ws + (24ull << 20));          // 16 MB  [64,2048,64] bf16 (pre-scaled)
  short* Kf    = (short*)(ws + (40ull << 20));          // 16 MB  frag-major
  short* Vf    = (short*)(ws + (56ull << 20));          // 16 MB  frag-major
  short* Ao    = (short*)(ws + (72ull << 20));          // 16 MB  [8192,1024] bf16

  cvt_kernel<<<(M_TOK * K_DIM / 4 + 255) / 256, 256, 0, stream>>>(x, Xb, M_TOK * K_DIM);
  dim3 tb(32, 8);
  transpose_cvt<<<dim3(N_QKV / 32, K_DIM / 32), tb, 0, stream>>>(Wqkv, Wqkvt, K_DIM, N_QKV);
  transpose_cvt<<<dim3(DMODEL / 32, K_DIM / 32), tb, 0, stream>>>(Wout, Woutt, K_DIM, DMODEL);

  // gemm0 split: Q+K columns (C^T epilogue) and V columns (normal epilogue)
  gemm_bt<0><<<dim3(M_TOK / 128, 16), 256, 0, stream>>>(
      Xb, Wqkvt, bqkv, Qb, Kf, nullptr, nullptr, M_TOK, N_QKV, K_DIM, 0);
  gemm_bt<1><<<dim3(M_TOK / 128, 8), 256, 0, stream>>>(
      Xb, Wqkvt, bqkv, nullptr, nullptr, Vf, nullptr, M_TOK, N_QKV, K_DIM, 16);

  attn_kernel<<<dim3(64, T_SEQ / 256), 256, 0, stream>>>(Qb, Kf, Vf, Ao);

  gemm_bt<2><<<dim3(M_TOK / 128, DMODEL / 128), 256, 0, stream>>>(
      Ao, Woutt, bout, nullptr, nullptr, nullptr, out, M_TOK, DMODEL, K_DIM, 0);
}

// Round 3
// 251.011 us; speedup vs baseline: 1.0671x; 1.0671x over previous
//
#include <hip/hip_runtime.h>
#include <hip/hip_bf16.h>
#include <stdint.h>

#define T_SEQ 2048
#define DMODEL 1024
#define NH 16
#define DKH 64
#define M_TOK 8192   // B*T
#define N_QKV 3072
#define K_DIM 1024

#define ATTN_SC (0.125f * 1.44269504f)  // 1/sqrt(64) * log2(e), folded into Q store

typedef __attribute__((ext_vector_type(8))) short short8;
typedef __attribute__((ext_vector_type(4))) short short4v;
typedef __attribute__((ext_vector_type(4))) float float4v;
typedef __attribute__((ext_vector_type(2))) unsigned int uint2v;

__device__ inline short bf16_bits(float f) {
  __hip_bfloat16 h = __float2bfloat16(f);
  short s;
  __builtin_memcpy(&s, &h, 2);
  return s;
}

// fast f32x4 -> bf16x4: round-half-up via +0x8000 then take hi16
__device__ inline short4v pack4_bf16_fast(float a, float b, float c, float d) {
  unsigned ua = __builtin_bit_cast(unsigned, a) + 0x8000u;
  unsigned ub = __builtin_bit_cast(unsigned, b) + 0x8000u;
  unsigned uc = __builtin_bit_cast(unsigned, c) + 0x8000u;
  unsigned ud = __builtin_bit_cast(unsigned, d) + 0x8000u;
  uint2v uu = {(ua >> 16) | (ub & 0xFFFF0000u),
               (uc >> 16) | (ud & 0xFFFF0000u)};
  return __builtin_bit_cast(short4v, uu);
}

__device__ inline void async_load16(const void* g, void* l) {
  __builtin_amdgcn_global_load_lds(
      (const __attribute__((address_space(1))) unsigned int*)g,
      (__attribute__((address_space(3))) unsigned int*)l,
      16, 0, 0);
}

// ---------------- preprocessing ----------------

__global__ __launch_bounds__(256) void cvt_kernel(const float* __restrict__ in,
                                                  short* __restrict__ out, int n) {
  int idx = (blockIdx.x * 256 + threadIdx.x) * 4;
  if (idx < n) {
    float4v v = *(const float4v*)(in + idx);
    short4v o;
    o[0] = bf16_bits(v[0]); o[1] = bf16_bits(v[1]);
    o[2] = bf16_bits(v[2]); o[3] = bf16_bits(v[3]);
    *(short4v*)(out + idx) = o;
  }
}

// in: [K][N] fp32 row-major  ->  out: [N][K] bf16 row-major
__global__ __launch_bounds__(256) void transpose_cvt(const float* __restrict__ in,
                                                     short* __restrict__ out,
                                                     int K, int N) {
  __shared__ float tile[32][33];
  int n0 = blockIdx.x * 32, k0 = blockIdx.y * 32;
  int tx = threadIdx.x, ty = threadIdx.y;  // (32,8)
  #pragma unroll
  for (int r = ty; r < 32; r += 8)
    tile[r][tx] = in[(size_t)(k0 + r) * N + n0 + tx];
  __syncthreads();
  #pragma unroll
  for (int r = ty; r < 32; r += 8)
    out[(size_t)(n0 + r) * K + k0 + tx] = bf16_bits(tile[tx][r]);
}

// ---------------- double-buffered GEMM: C[M,N] = A[M,K] * Bt[N,K]^T + bias ----
// LDS chunk-rotation swizzle: 16-B chunk c of row r lives at slot (c+(r>>1))&3
// -> every b128 frag-read quarter-phase hits 2 words/bank (conflict-free).
// Staging stays a linear DMA; the lane's GLOBAL chunk offset is permuted.
// EPI 0: Q+K scatter, C^T orientation (lane holds 4 consecutive dk) -> vec stores
//   Qb [B*H, T, 64]  (row-major, PRE-SCALED by ATTN_SC)
//   Kf [B*H, kb64, c(4), h(2), quad(4), l16(16), w(8)]    (fragment-major)
// EPI 1: V scatter, normal orientation (lane holds 4 consecutive tokens)
//   Vf [B*H, kb64, c(4), d(4), quad(4), l16(16), kk(4)]   (fragment-major)
// EPI 2: fp32 C^T epilogue -> Cout [M,N] via float4
// Grid: x = M-tile -> XCD = m%8 (per-XCD L2 keeps the A-stripe hot).

template <int EPI>
__global__ __launch_bounds__(256) void gemm_bt(
    const short* __restrict__ A, const short* __restrict__ Bt,
    const float* __restrict__ bias,
    short* __restrict__ Qb, short* __restrict__ Kf, short* __restrict__ Vf,
    float* __restrict__ Cout, int M, int N, int K, int ntile0) {
  constexpr bool CT = (EPI != 1);
  __shared__ __align__(16) short AsB[2][128 * 32];
  __shared__ __align__(16) short BsB[2][128 * 32];
  const int tid = threadIdx.x;
  const int lane = tid & 63;
  const int wave = tid >> 6;
  const int m0 = blockIdx.x * 128;
  const int n0 = (blockIdx.y + ntile0) * 128;
  const int wm = (wave >> 1) * 64;
  const int wn = (wave & 1) * 64;
  const int quad = lane >> 4;
  const int l16 = lane & 15;

  float4v acc[4][4] = {};

  // staging: lane covers LDS chunk p=tid (and p=tid+256); row=p>>2, slot=p&3;
  // global chunk c = (slot - (row>>1)) & 3  (lane-constant swizzle offset)
  const int r0 = tid >> 2, r1 = r0 + 64;
  const int oswz = (((tid & 3) - (tid >> 3)) & 3) * 8;
  const int lo0 = wave * 512;
  const int lo1 = 2048 + wave * 512;

  const short* Ag0 = A  + (size_t)(m0 + r0) * K + oswz;
  const short* Ag1 = A  + (size_t)(m0 + r1) * K + oswz;
  const short* Bg0 = Bt + (size_t)(n0 + r0) * K + oswz;
  const short* Bg1 = Bt + (size_t)(n0 + r1) * K + oswz;

  // frag-read swizzle offset (lane-constant): slot = (quad + (row>>1)) & 3
  const int sw = ((quad + (l16 >> 1)) & 3) * 8;

  // prologue: stage K-tile 0 into buffer 0
  async_load16(Ag0, &AsB[0][0] + lo0);
  async_load16(Ag1, &AsB[0][0] + lo1);
  async_load16(Bg0, &BsB[0][0] + lo0);
  async_load16(Bg1, &BsB[0][0] + lo1);

  const int nkt = K >> 5;
  for (int it = 0; it < nkt; ++it) {
    __builtin_amdgcn_s_waitcnt(0);   // this tile's DMA complete
    __syncthreads();                 // visible to all; prev buffer free

    if (it + 1 < nkt) {              // prefetch next K-tile into other buffer
      const int kt = (it + 1) << 5;
      const int nb = (it + 1) & 1;
      async_load16(Ag0 + kt, &AsB[nb][0] + lo0);
      async_load16(Ag1 + kt, &AsB[nb][0] + lo1);
      async_load16(Bg0 + kt, &BsB[nb][0] + lo0);
      async_load16(Bg1 + kt, &BsB[nb][0] + lo1);
    }

    const short* As = &AsB[it & 1][0];
    const short* Bs = &BsB[it & 1][0];
    short8 af[4], bfr[4];
    #pragma unroll
    for (int t = 0; t < 4; ++t)
      af[t] = *(const short8*)(As + (size_t)(wm + t * 16 + l16) * 32 + sw);
    #pragma unroll
    for (int t = 0; t < 4; ++t)
      bfr[t] = *(const short8*)(Bs + (size_t)(wn + t * 16 + l16) * 32 + sw);
    #pragma unroll
    for (int i = 0; i < 4; ++i)
      #pragma unroll
      for (int j = 0; j < 4; ++j) {
        if (CT)
          acc[i][j] = __builtin_amdgcn_mfma_f32_16x16x32_bf16(bfr[j], af[i], acc[i][j], 0, 0, 0);
        else
          acc[i][j] = __builtin_amdgcn_mfma_f32_16x16x32_bf16(af[i], bfr[j], acc[i][j], 0, 0, 0);
      }
  }

  if (EPI == 0) {
    // C^T: reg i = col (dk) colb+i, lane l16 = token
    const int which = n0 >> 10;      // 0:q 1:k (uniform per block)
    #pragma unroll
    for (int tj = 0; tj < 4; ++tj) {
      const int colb = n0 + wn + tj * 16 + quad * 4;   // 4 consecutive cols
      float4v bz = *(const float4v*)(bias + colb);
      const int d = colb & 1023;
      const int h = d >> 6, dkb = d & 63;
      #pragma unroll
      for (int ti = 0; ti < 4; ++ti) {
        const int tok = m0 + wm + ti * 16 + l16;
        const int b = tok >> 11, t = tok & 2047;
        const size_t bhoff = (size_t)(b * NH + h) * (T_SEQ * DKH);
        float4v v = acc[ti][tj];
        if (which == 0) {
          short4v o = pack4_bf16_fast((v[0] + bz[0]) * ATTN_SC, (v[1] + bz[1]) * ATTN_SC,
                                      (v[2] + bz[2]) * ATTN_SC, (v[3] + bz[3]) * ATTN_SC);
          *(short4v*)(Qb + bhoff + (size_t)t * DKH + dkb) = o;
        } else {
          short4v o = pack4_bf16_fast(v[0] + bz[0], v[1] + bz[1], v[2] + bz[2], v[3] + bz[3]);
          const int h2 = dkb >> 5, qd = (dkb >> 3) & 3, w = dkb & 7;
          size_t kbase = bhoff + (size_t)(t >> 6) * 4096 +
                         ((((t >> 4) & 3) * 2 + h2) * 4 + qd) * 128 + (t & 15) * 8 + w;
          *(short4v*)(Kf + kbase) = o;
        }
      }
    }
  } else if (EPI == 1) {
    // normal C: reg i = token rbase+i, lane l16 = col
    #pragma unroll
    for (int tj = 0; tj < 4; ++tj) {
      const int col = n0 + wn + tj * 16 + l16;
      const float bz = bias[col];
      const int d = col & 1023;
      const int h = d >> 6, dk = d & 63;
      #pragma unroll
      for (int ti = 0; ti < 4; ++ti) {
        const int rbase = m0 + wm + ti * 16 + quad * 4;
        const int b = rbase >> 11, t = rbase & 2047;
        const size_t bhoff = (size_t)(b * NH + h) * (T_SEQ * DKH);
        float4v v = acc[ti][tj];
        short4v pv = pack4_bf16_fast(v[0] + bz, v[1] + bz, v[2] + bz, v[3] + bz);
        size_t off = bhoff + (size_t)(t >> 6) * 4096 +
                     ((((t >> 4) & 3) * 4 + (dk >> 4)) * 4 + ((t >> 2) & 3)) * 64 +
                     (dk & 15) * 4;
        *(short4v*)(Vf + off) = pv;
      }
    }
  } else {
    // C^T fp32: float4 along cols, lane l16 = row
    #pragma unroll
    for (int tj = 0; tj < 4; ++tj) {
      const int colb = n0 + wn + tj * 16 + quad * 4;
      float4v bz = *(const float4v*)(bias + colb);
      #pragma unroll
      for (int ti = 0; ti < 4; ++ti) {
        const int row = m0 + wm + ti * 16 + l16;
        float4v v = acc[ti][tj];
        float4v o = {v[0] + bz[0], v[1] + bz[1], v[2] + bz[2], v[3] + bz[3]};
        *(float4v*)(Cout + (size_t)row * N + colb) = o;
      }
    }
  }
}

// ---------------- flash attention (S^T, max-free, register PV, frag-major KV) --
// Block = 4 waves = 128 q rows of one (b,h); wave = 32 q rows.
// S^T = K·Q^T (C: row=key=quad*4+i, col=q=l16); P stays in registers as the
// B-frag of mfma_16x16x16bf16_1k; O^T += V^T·P; l via ones-row MFMA.
// exp2 via raw v_exp_f32; P bf16 via round-half-up truncation.

template <int MASK>
__device__ __forceinline__ void attn_tile(
    const short* __restrict__ Ks, const short* __restrict__ Vs,
    const short8 aq[2][2], short4v ones,
    float4v oc[2][4], float4v lc[2],
    int dkq, int quad, int l16) {
  const int mb = dkq + quad * 4 - l16;   // mask base (only used if MASK)
  #pragma unroll
  for (int c = 0; c < 4; ++c) {
    short8 b0 = *(const short8*)(Ks + (c * 2 + 0) * 512 + quad * 128 + l16 * 8);
    short8 b1 = *(const short8*)(Ks + (c * 2 + 1) * 512 + quad * 128 + l16 * 8);
    short4v vf[4];
    #pragma unroll
    for (int d = 0; d < 4; ++d)
      vf[d] = *(const short4v*)(Vs + (c * 4 + d) * 256 + quad * 64 + l16 * 4);
    #pragma unroll
    for (int qi = 0; qi < 2; ++qi) {
      float4v z = {0.f, 0.f, 0.f, 0.f};
      z = __builtin_amdgcn_mfma_f32_16x16x32_bf16(b0, aq[qi][0], z, 0, 0, 0);
      z = __builtin_amdgcn_mfma_f32_16x16x32_bf16(b1, aq[qi][1], z, 0, 0, 0);
      float p[4];
      #pragma unroll
      for (int i = 0; i < 4; ++i) {
        p[i] = __builtin_amdgcn_exp2f(z[i]);   // Q pre-scaled by 1/sqrt(dk)*log2e
        if (MASK && (mb + c * 16 + i - qi * 16 > 0)) p[i] = 0.f;
      }
      short4v pb = pack4_bf16_fast(p[0], p[1], p[2], p[3]);
      lc[qi] = __builtin_amdgcn_mfma_f32_16x16x16bf16_1k(ones, pb, lc[qi], 0, 0, 0);
      #pragma unroll
      for (int d = 0; d < 4; ++d)
        oc[qi][d] = __builtin_amdgcn_mfma_f32_16x16x16bf16_1k(vf[d], pb, oc[qi][d], 0, 0, 0);
    }
  }
}

__global__ __launch_bounds__(256) void attn_kernel(const short* __restrict__ Qb,
                                                   const short* __restrict__ Kf,
                                                   const short* __restrict__ Vf,
                                                   short* __restrict__ Ao) {
  __shared__ __align__(16) short KsB[2][4096];   // 2 x 8 KB
  __shared__ __align__(16) short VsB[2][4096];   // 2 x 8 KB
  const int bh = blockIdx.x;                 // 0..63 -> XCD = bh&7 (balance + L2 pin)
  const int y = blockIdx.y;                  // 0..15
  // Balanced-class mapping: bijection on 0..15 whose every mod-4 residue class
  // {y, y+4, y+8, y+12} has qb-sum 30 (= mean) -> each CU's 4 resident blocks
  // carry equal total work (68 tile-iters) instead of 56..80. Longest-first
  // within each class (heavy blocks dispatched earliest).
  const int qb = (y < 4) ? (15 - y) : (y < 8) ? (y - 4) : (y < 12) ? (19 - y) : (y - 8);
  const int tid = threadIdx.x;
  const int lane = tid & 63, wave = tid >> 6;
  const int quad = lane >> 4, l16 = lane & 15;
  const int qw0 = qb * 128 + wave * 32;      // this wave's first q row
  const int nkb = 2 * qb + 2;

  const short* Qg = Qb + ((size_t)bh * T_SEQ + qw0) * DKH;
  const short* Kg0 = Kf + (size_t)bh * (T_SEQ * DKH);
  const short* Vg0 = Vf + (size_t)bh * (T_SEQ * DKH);

  // Q fragments (B-operand of S^T mfma): [q=l16][k dim=quad*8+j]
  short8 aq[2][2];
  #pragma unroll
  for (int qi = 0; qi < 2; ++qi)
    #pragma unroll
    for (int h = 0; h < 2; ++h)
      aq[qi][h] = *(const short8*)(Qg + (size_t)(qi * 16 + l16) * DKH + h * 32 + quad * 8);

  float4v oc[2][4] = {};     // O^T: row d = quad*4+i (+16*dblk), col q = l16
  float4v lc[2] = {};        // ones-row MFMA accumulators: every reg = l(q=l16)
  short4v ones = {0x3F80, 0x3F80, 0x3F80, 0x3F80};   // bf16 1.0 x4

  // stage tile 0 into buffer 0 (linear 8KB copies)
  async_load16(Kg0 + tid * 8,        &KsB[0][0] + wave * 512);
  async_load16(Kg0 + 2048 + tid * 8, &KsB[0][0] + 2048 + wave * 512);
  async_load16(Vg0 + tid * 8,        &VsB[0][0] + wave * 512);
  async_load16(Vg0 + 2048 + tid * 8, &VsB[0][0] + 2048 + wave * 512);

  for (int kb = 0; kb < nkb; ++kb) {
    __builtin_amdgcn_s_waitcnt(0);   // drain this tile's DMA
    __syncthreads();

    if (kb + 1 < nkb) {              // prefetch next tile into other buffer
      const int nb = (kb + 1) & 1;
      const short* Kg = Kg0 + (size_t)(kb + 1) * 4096;
      const short* Vg = Vg0 + (size_t)(kb + 1) * 4096;
      async_load16(Kg + tid * 8,        &KsB[nb][0] + wave * 512);
      async_load16(Kg + 2048 + tid * 8, &KsB[nb][0] + 2048 + wave * 512);
      async_load16(Vg + tid * 8,        &VsB[nb][0] + wave * 512);
      async_load16(Vg + 2048 + tid * 8, &VsB[nb][0] + 2048 + wave * 512);
    }

    const int dkq = kb * 64 - qw0;   // wave-uniform
    if (dkq + 63 <= 0) {             // fully-causal tile: no mask ops
      attn_tile<0>(&KsB[kb & 1][0], &VsB[kb & 1][0], aq, ones, oc, lc, dkq, quad, l16);
    } else if (dkq <= 31) {          // diagonal tile (exactly one per wave)
      attn_tile<1>(&KsB[kb & 1][0], &VsB[kb & 1][0], aq, ones, oc, lc, dkq, quad, l16);
    }                                // else: fully above diagonal -> skip
  }

  const int b = bh >> 4, h = bh & 15;
  #pragma unroll
  for (int qi = 0; qi < 2; ++qi) {
    float rl = 1.0f / lc[qi][0];     // every reg/lane of lc = row-sum l(q=l16)
    #pragma unroll
    for (int d = 0; d < 4; ++d) {
      short4v o;
      #pragma unroll
      for (int i = 0; i < 4; ++i) o[i] = bf16_bits(oc[qi][d][i] * rl);
      int t = qw0 + qi * 16 + l16;
      *(short4v*)(Ao + (size_t)(b * T_SEQ + t) * DMODEL + h * DKH + d * 16 + quad * 4) = o;
    }
  }
}

// ---------------- launch ----------------

extern "C" void kernel_launch(void* const* d_in, const int* in_sizes, int n_in,
                              void* d_out, int out_size, void* d_ws, size_t ws_size,
                              hipStream_t stream) {
  const float* x    = (const float*)d_in[0];
  const float* Wqkv = (const float*)d_in[1];
  const float* bqkv = (const float*)d_in[2];
  const float* Wout = (const float*)d_in[3];
  const float* bout = (const float*)d_in[4];
  float* out = (float*)d_out;

  char* ws = (char*)d_ws;
  short* Xb    = (short*)(ws);                          // 16 MB  [8192,1024] bf16
  short* Wqkvt = (short*)(ws + (16ull << 20));          //  6 MB  [3072,1024] bf16
  short* Woutt = (short*)(ws + (22ull << 20));          //  2 MB  [1024,1024] bf16
  short* Qb    = (short*)(ws + (24ull << 20));          // 16 MB  [64,2048,64] bf16 (pre-scaled)
  short* Kf    = (short*)(ws + (40ull << 20));          // 16 MB  frag-major
  short* Vf    = (short*)(ws + (56ull << 20));          // 16 MB  frag-major
  short* Ao    = (short*)(ws + (72ull << 20));          // 16 MB  [8192,1024] bf16

  cvt_kernel<<<(M_TOK * K_DIM / 4 + 255) / 256, 256, 0, stream>>>(x, Xb, M_TOK * K_DIM);
  dim3 tb(32, 8);
  transpose_cvt<<<dim3(N_QKV / 32, K_DIM / 32), tb, 0, stream>>>(Wqkv, Wqkvt, K_DIM, N_QKV);
  transpose_cvt<<<dim3(DMODEL / 32, K_DIM / 32), tb, 0, stream>>>(Wout, Woutt, K_DIM, DMODEL);

  // gemm0 split: Q+K columns (C^T epilogue) and V columns (normal epilogue)
  gemm_bt<0><<<dim3(M_TOK / 128, 16), 256, 0, stream>>>(
      Xb, Wqkvt, bqkv, Qb, Kf, nullptr, nullptr, M_TOK, N_QKV, K_DIM, 0);
  gemm_bt<1><<<dim3(M_TOK / 128, 8), 256, 0, stream>>>(
      Xb, Wqkvt, bqkv, nullptr, nullptr, Vf, nullptr, M_TOK, N_QKV, K_DIM, 16);

  attn_kernel<<<dim3(64, T_SEQ / 128), 256, 0, stream>>>(Qb, Kf, Vf, Ao);

  gemm_bt<2><<<dim3(M_TOK / 128, DMODEL / 128), 256, 0, stream>>>(
      Ao, Woutt, bout, nullptr, nullptr, nullptr, out, M_TOK, DMODEL, K_DIM, 0);
}

// Round 4
// 243.241 us; speedup vs baseline: 1.1012x; 1.0319x over previous
//
#include <hip/hip_runtime.h>
#include <hip/hip_bf16.h>
#include <stdint.h>

#define T_SEQ 2048
#define DMODEL 1024
#define NH 16
#define DKH 64
#define M_TOK 8192   // B*T
#define N_QKV 3072
#define K_DIM 1024

#define ATTN_SC (0.125f * 1.44269504f)  // 1/sqrt(64) * log2(e), folded into Q store

typedef __attribute__((ext_vector_type(8))) short short8;
typedef __attribute__((ext_vector_type(4))) short short4v;
typedef __attribute__((ext_vector_type(4))) float float4v;
typedef __attribute__((ext_vector_type(2))) unsigned int uint2v;

__device__ inline short bf16_bits(float f) {
  __hip_bfloat16 h = __float2bfloat16(f);
  short s;
  __builtin_memcpy(&s, &h, 2);
  return s;
}

// fast f32x4 -> bf16x4: round-half-up via +0x8000 then take hi16
__device__ inline short4v pack4_bf16_fast(float a, float b, float c, float d) {
  unsigned ua = __builtin_bit_cast(unsigned, a) + 0x8000u;
  unsigned ub = __builtin_bit_cast(unsigned, b) + 0x8000u;
  unsigned uc = __builtin_bit_cast(unsigned, c) + 0x8000u;
  unsigned ud = __builtin_bit_cast(unsigned, d) + 0x8000u;
  uint2v uu = {(ua >> 16) | (ub & 0xFFFF0000u),
               (uc >> 16) | (ud & 0xFFFF0000u)};
  return __builtin_bit_cast(short4v, uu);
}

// truncating f32x4 -> bf16x4 via v_perm_b32: 2 VALU per 4 values.
// D = {b.hi16 : a.hi16}; sel byte 0..3 picks S1 bytes, 4..7 picks S0 bytes.
// Used only on the attention P-path: P>=0 and the same truncated P feeds both
// numerator (P*V) and denominator (sum P), so the -0.5ulp bias cancels in O.
__device__ inline short4v pack4_bf16_trunc(float a, float b, float c, float d) {
  unsigned ua = __builtin_bit_cast(unsigned, a);
  unsigned ub = __builtin_bit_cast(unsigned, b);
  unsigned uc = __builtin_bit_cast(unsigned, c);
  unsigned ud = __builtin_bit_cast(unsigned, d);
  uint2v uu = {__builtin_amdgcn_perm(ub, ua, 0x07060302u),
               __builtin_amdgcn_perm(ud, uc, 0x07060302u)};
  return __builtin_bit_cast(short4v, uu);
}

__device__ inline void async_load16(const void* g, void* l) {
  __builtin_amdgcn_global_load_lds(
      (const __attribute__((address_space(1))) unsigned int*)g,
      (__attribute__((address_space(3))) unsigned int*)l,
      16, 0, 0);
}

// ---------------- preprocessing ----------------

__global__ __launch_bounds__(256) void cvt_kernel(const float* __restrict__ in,
                                                  short* __restrict__ out, int n) {
  int idx = (blockIdx.x * 256 + threadIdx.x) * 4;
  if (idx < n) {
    float4v v = *(const float4v*)(in + idx);
    short4v o;
    o[0] = bf16_bits(v[0]); o[1] = bf16_bits(v[1]);
    o[2] = bf16_bits(v[2]); o[3] = bf16_bits(v[3]);
    *(short4v*)(out + idx) = o;
  }
}

// in: [K][N] fp32 row-major  ->  out: [N][K] bf16 row-major
__global__ __launch_bounds__(256) void transpose_cvt(const float* __restrict__ in,
                                                     short* __restrict__ out,
                                                     int K, int N) {
  __shared__ float tile[32][33];
  int n0 = blockIdx.x * 32, k0 = blockIdx.y * 32;
  int tx = threadIdx.x, ty = threadIdx.y;  // (32,8)
  #pragma unroll
  for (int r = ty; r < 32; r += 8)
    tile[r][tx] = in[(size_t)(k0 + r) * N + n0 + tx];
  __syncthreads();
  #pragma unroll
  for (int r = ty; r < 32; r += 8)
    out[(size_t)(n0 + r) * K + k0 + tx] = bf16_bits(tile[tx][r]);
}

// ---------------- double-buffered GEMM: C[M,N] = A[M,K] * Bt[N,K]^T + bias ----
// LDS chunk-rotation swizzle: 16-B chunk c of row r lives at slot (c+(r>>1))&3
// -> every b128 frag-read quarter-phase hits 2 words/bank (conflict-free).
// Staging stays a linear DMA; the lane's GLOBAL chunk offset is permuted.
// EPI 0: Q+K scatter, C^T orientation (lane holds 4 consecutive dk) -> vec stores
//   Qb [B*H, T, 64]  (row-major, PRE-SCALED by ATTN_SC)
//   Kf [B*H, kb64, c(4), h(2), quad(4), l16(16), w(8)]    (fragment-major)
// EPI 1: V scatter, normal orientation (lane holds 4 consecutive tokens)
//   Vf [B*H, kb64, c(4), d(4), quad(4), l16(16), kk(4)]   (fragment-major)
// EPI 2: fp32 C^T epilogue -> Cout [M,N] via float4
// Grid: x = M-tile -> XCD = m%8 (per-XCD L2 keeps the A-stripe hot).

template <int EPI>
__global__ __launch_bounds__(256) void gemm_bt(
    const short* __restrict__ A, const short* __restrict__ Bt,
    const float* __restrict__ bias,
    short* __restrict__ Qb, short* __restrict__ Kf, short* __restrict__ Vf,
    float* __restrict__ Cout, int M, int N, int K, int ntile0) {
  constexpr bool CT = (EPI != 1);
  __shared__ __align__(16) short AsB[2][128 * 32];
  __shared__ __align__(16) short BsB[2][128 * 32];
  const int tid = threadIdx.x;
  const int lane = tid & 63;
  const int wave = tid >> 6;
  const int m0 = blockIdx.x * 128;
  const int n0 = (blockIdx.y + ntile0) * 128;
  const int wm = (wave >> 1) * 64;
  const int wn = (wave & 1) * 64;
  const int quad = lane >> 4;
  const int l16 = lane & 15;

  float4v acc[4][4] = {};

  // staging: lane covers LDS chunk p=tid (and p=tid+256); row=p>>2, slot=p&3;
  // global chunk c = (slot - (row>>1)) & 3  (lane-constant swizzle offset)
  const int r0 = tid >> 2, r1 = r0 + 64;
  const int oswz = (((tid & 3) - (tid >> 3)) & 3) * 8;
  const int lo0 = wave * 512;
  const int lo1 = 2048 + wave * 512;

  const short* Ag0 = A  + (size_t)(m0 + r0) * K + oswz;
  const short* Ag1 = A  + (size_t)(m0 + r1) * K + oswz;
  const short* Bg0 = Bt + (size_t)(n0 + r0) * K + oswz;
  const short* Bg1 = Bt + (size_t)(n0 + r1) * K + oswz;

  // frag-read swizzle offset (lane-constant): slot = (quad + (row>>1)) & 3
  const int sw = ((quad + (l16 >> 1)) & 3) * 8;

  // prologue: stage K-tile 0 into buffer 0
  async_load16(Ag0, &AsB[0][0] + lo0);
  async_load16(Ag1, &AsB[0][0] + lo1);
  async_load16(Bg0, &BsB[0][0] + lo0);
  async_load16(Bg1, &BsB[0][0] + lo1);

  const int nkt = K >> 5;
  for (int it = 0; it < nkt; ++it) {
    __builtin_amdgcn_s_waitcnt(0);   // this tile's DMA complete
    __syncthreads();                 // visible to all; prev buffer free

    if (it + 1 < nkt) {              // prefetch next K-tile into other buffer
      const int kt = (it + 1) << 5;
      const int nb = (it + 1) & 1;
      async_load16(Ag0 + kt, &AsB[nb][0] + lo0);
      async_load16(Ag1 + kt, &AsB[nb][0] + lo1);
      async_load16(Bg0 + kt, &BsB[nb][0] + lo0);
      async_load16(Bg1 + kt, &BsB[nb][0] + lo1);
    }

    const short* As = &AsB[it & 1][0];
    const short* Bs = &BsB[it & 1][0];
    short8 af[4], bfr[4];
    #pragma unroll
    for (int t = 0; t < 4; ++t)
      af[t] = *(const short8*)(As + (size_t)(wm + t * 16 + l16) * 32 + sw);
    #pragma unroll
    for (int t = 0; t < 4; ++t)
      bfr[t] = *(const short8*)(Bs + (size_t)(wn + t * 16 + l16) * 32 + sw);
    #pragma unroll
    for (int i = 0; i < 4; ++i)
      #pragma unroll
      for (int j = 0; j < 4; ++j) {
        if (CT)
          acc[i][j] = __builtin_amdgcn_mfma_f32_16x16x32_bf16(bfr[j], af[i], acc[i][j], 0, 0, 0);
        else
          acc[i][j] = __builtin_amdgcn_mfma_f32_16x16x32_bf16(af[i], bfr[j], acc[i][j], 0, 0, 0);
      }
  }

  if (EPI == 0) {
    // C^T: reg i = col (dk) colb+i, lane l16 = token
    const int which = n0 >> 10;      // 0:q 1:k (uniform per block)
    #pragma unroll
    for (int tj = 0; tj < 4; ++tj) {
      const int colb = n0 + wn + tj * 16 + quad * 4;   // 4 consecutive cols
      float4v bz = *(const float4v*)(bias + colb);
      const int d = colb & 1023;
      const int h = d >> 6, dkb = d & 63;
      #pragma unroll
      for (int ti = 0; ti < 4; ++ti) {
        const int tok = m0 + wm + ti * 16 + l16;
        const int b = tok >> 11, t = tok & 2047;
        const size_t bhoff = (size_t)(b * NH + h) * (T_SEQ * DKH);
        float4v v = acc[ti][tj];
        if (which == 0) {
          short4v o = pack4_bf16_fast((v[0] + bz[0]) * ATTN_SC, (v[1] + bz[1]) * ATTN_SC,
                                      (v[2] + bz[2]) * ATTN_SC, (v[3] + bz[3]) * ATTN_SC);
          *(short4v*)(Qb + bhoff + (size_t)t * DKH + dkb) = o;
        } else {
          short4v o = pack4_bf16_fast(v[0] + bz[0], v[1] + bz[1], v[2] + bz[2], v[3] + bz[3]);
          const int h2 = dkb >> 5, qd = (dkb >> 3) & 3, w = dkb & 7;
          size_t kbase = bhoff + (size_t)(t >> 6) * 4096 +
                         ((((t >> 4) & 3) * 2 + h2) * 4 + qd) * 128 + (t & 15) * 8 + w;
          *(short4v*)(Kf + kbase) = o;
        }
      }
    }
  } else if (EPI == 1) {
    // normal C: reg i = token rbase+i, lane l16 = col
    #pragma unroll
    for (int tj = 0; tj < 4; ++tj) {
      const int col = n0 + wn + tj * 16 + l16;
      const float bz = bias[col];
      const int d = col & 1023;
      const int h = d >> 6, dk = d & 63;
      #pragma unroll
      for (int ti = 0; ti < 4; ++ti) {
        const int rbase = m0 + wm + ti * 16 + quad * 4;
        const int b = rbase >> 11, t = rbase & 2047;
        const size_t bhoff = (size_t)(b * NH + h) * (T_SEQ * DKH);
        float4v v = acc[ti][tj];
        short4v pv = pack4_bf16_fast(v[0] + bz, v[1] + bz, v[2] + bz, v[3] + bz);
        size_t off = bhoff + (size_t)(t >> 6) * 4096 +
                     ((((t >> 4) & 3) * 4 + (dk >> 4)) * 4 + ((t >> 2) & 3)) * 64 +
                     (dk & 15) * 4;
        *(short4v*)(Vf + off) = pv;
      }
    }
  } else {
    // C^T fp32: float4 along cols, lane l16 = row
    #pragma unroll
    for (int tj = 0; tj < 4; ++tj) {
      const int colb = n0 + wn + tj * 16 + quad * 4;
      float4v bz = *(const float4v*)(bias + colb);
      #pragma unroll
      for (int ti = 0; ti < 4; ++ti) {
        const int row = m0 + wm + ti * 16 + l16;
        float4v v = acc[ti][tj];
        float4v o = {v[0] + bz[0], v[1] + bz[1], v[2] + bz[2], v[3] + bz[3]};
        *(float4v*)(Cout + (size_t)row * N + colb) = o;
      }
    }
  }
}

// ---------------- flash attention (S^T, max-free, register PV, frag-major KV) --
// Block = 4 waves = 128 q rows of one (b,h); wave = 32 q rows.
// S^T = K·Q^T (C: row=key=quad*4+i, col=q=l16); P stays in registers as the
// B-frag of mfma_16x16x16bf16_1k; O^T += V^T·P; l via ones-row MFMA.
// exp2 via raw v_exp_f32; P bf16 via v_perm_b32 truncation (2 VALU / 4 vals).

template <int MASK>
__device__ __forceinline__ void attn_tile(
    const short* __restrict__ Ks, const short* __restrict__ Vs,
    const short8 aq[2][2], short4v ones,
    float4v oc[2][4], float4v lc[2],
    int dkq, int quad, int l16) {
  const int mb = dkq + quad * 4 - l16;   // mask base (only used if MASK)
  #pragma unroll
  for (int c = 0; c < 4; ++c) {
    short8 b0 = *(const short8*)(Ks + (c * 2 + 0) * 512 + quad * 128 + l16 * 8);
    short8 b1 = *(const short8*)(Ks + (c * 2 + 1) * 512 + quad * 128 + l16 * 8);
    short4v vf[4];
    #pragma unroll
    for (int d = 0; d < 4; ++d)
      vf[d] = *(const short4v*)(Vs + (c * 4 + d) * 256 + quad * 64 + l16 * 4);
    #pragma unroll
    for (int qi = 0; qi < 2; ++qi) {
      float4v z = {0.f, 0.f, 0.f, 0.f};
      z = __builtin_amdgcn_mfma_f32_16x16x32_bf16(b0, aq[qi][0], z, 0, 0, 0);
      z = __builtin_amdgcn_mfma_f32_16x16x32_bf16(b1, aq[qi][1], z, 0, 0, 0);
      float p[4];
      #pragma unroll
      for (int i = 0; i < 4; ++i) {
        p[i] = __builtin_amdgcn_exp2f(z[i]);   // Q pre-scaled by 1/sqrt(dk)*log2e
        if (MASK && (mb + c * 16 + i - qi * 16 > 0)) p[i] = 0.f;
      }
      short4v pb = pack4_bf16_trunc(p[0], p[1], p[2], p[3]);
      lc[qi] = __builtin_amdgcn_mfma_f32_16x16x16bf16_1k(ones, pb, lc[qi], 0, 0, 0);
      #pragma unroll
      for (int d = 0; d < 4; ++d)
        oc[qi][d] = __builtin_amdgcn_mfma_f32_16x16x16bf16_1k(vf[d], pb, oc[qi][d], 0, 0, 0);
    }
  }
}

__global__ __launch_bounds__(256) void attn_kernel(const short* __restrict__ Qb,
                                                   const short* __restrict__ Kf,
                                                   const short* __restrict__ Vf,
                                                   short* __restrict__ Ao) {
  __shared__ __align__(16) short KsB[2][4096];   // 2 x 8 KB
  __shared__ __align__(16) short VsB[2][4096];   // 2 x 8 KB
  const int bh = blockIdx.x;                 // 0..63 -> XCD = bh&7 (balance + L2 pin)
  const int y = blockIdx.y;                  // 0..15
  // Balanced-class mapping: bijection on 0..15 whose every mod-4 residue class
  // {y, y+4, y+8, y+12} has qb-sum 30 (= mean) -> each CU's 4 resident blocks
  // carry equal total work (68 tile-iters) instead of 56..80. Longest-first
  // within each class (heavy blocks dispatched earliest).
  const int qb = (y < 4) ? (15 - y) : (y < 8) ? (y - 4) : (y < 12) ? (19 - y) : (y - 8);
  const int tid = threadIdx.x;
  const int lane = tid & 63, wave = tid >> 6;
  const int quad = lane >> 4, l16 = lane & 15;
  const int qw0 = qb * 128 + wave * 32;      // this wave's first q row
  const int nkb = 2 * qb + 2;

  const short* Qg = Qb + ((size_t)bh * T_SEQ + qw0) * DKH;
  const short* Kg0 = Kf + (size_t)bh * (T_SEQ * DKH);
  const short* Vg0 = Vf + (size_t)bh * (T_SEQ * DKH);

  // Q fragments (B-operand of S^T mfma): [q=l16][k dim=quad*8+j]
  short8 aq[2][2];
  #pragma unroll
  for (int qi = 0; qi < 2; ++qi)
    #pragma unroll
    for (int h = 0; h < 2; ++h)
      aq[qi][h] = *(const short8*)(Qg + (size_t)(qi * 16 + l16) * DKH + h * 32 + quad * 8);

  float4v oc[2][4] = {};     // O^T: row d = quad*4+i (+16*dblk), col q = l16
  float4v lc[2] = {};        // ones-row MFMA accumulators: every reg = l(q=l16)
  short4v ones = {0x3F80, 0x3F80, 0x3F80, 0x3F80};   // bf16 1.0 x4

  // stage tile 0 into buffer 0 (linear 8KB copies)
  async_load16(Kg0 + tid * 8,        &KsB[0][0] + wave * 512);
  async_load16(Kg0 + 2048 + tid * 8, &KsB[0][0] + 2048 + wave * 512);
  async_load16(Vg0 + tid * 8,        &VsB[0][0] + wave * 512);
  async_load16(Vg0 + 2048 + tid * 8, &VsB[0][0] + 2048 + wave * 512);

  for (int kb = 0; kb < nkb; ++kb) {
    __builtin_amdgcn_s_waitcnt(0);   // drain this tile's DMA
    __syncthreads();

    if (kb + 1 < nkb) {              // prefetch next tile into other buffer
      const int nb = (kb + 1) & 1;
      const short* Kg = Kg0 + (size_t)(kb + 1) * 4096;
      const short* Vg = Vg0 + (size_t)(kb + 1) * 4096;
      async_load16(Kg + tid * 8,        &KsB[nb][0] + wave * 512);
      async_load16(Kg + 2048 + tid * 8, &KsB[nb][0] + 2048 + wave * 512);
      async_load16(Vg + tid * 8,        &VsB[nb][0] + wave * 512);
      async_load16(Vg + 2048 + tid * 8, &VsB[nb][0] + 2048 + wave * 512);
    }

    const int dkq = kb * 64 - qw0;   // wave-uniform
    if (dkq + 63 <= 0) {             // fully-causal tile: no mask ops
      attn_tile<0>(&KsB[kb & 1][0], &VsB[kb & 1][0], aq, ones, oc, lc, dkq, quad, l16);
    } else if (dkq <= 31) {          // diagonal tile (exactly one per wave)
      attn_tile<1>(&KsB[kb & 1][0], &VsB[kb & 1][0], aq, ones, oc, lc, dkq, quad, l16);
    }                                // else: fully above diagonal -> skip
  }

  const int b = bh >> 4, h = bh & 15;
  #pragma unroll
  for (int qi = 0; qi < 2; ++qi) {
    float rl = 1.0f / lc[qi][0];     // every reg/lane of lc = row-sum l(q=l16)
    #pragma unroll
    for (int d = 0; d < 4; ++d) {
      short4v o;
      #pragma unroll
      for (int i = 0; i < 4; ++i) o[i] = bf16_bits(oc[qi][d][i] * rl);
      int t = qw0 + qi * 16 + l16;
      *(short4v*)(Ao + (size_t)(b * T_SEQ + t) * DMODEL + h * DKH + d * 16 + quad * 4) = o;
    }
  }
}

// ---------------- launch ----------------

extern "C" void kernel_launch(void* const* d_in, const int* in_sizes, int n_in,
                              void* d_out, int out_size, void* d_ws, size_t ws_size,
                              hipStream_t stream) {
  const float* x    = (const float*)d_in[0];
  const float* Wqkv = (const float*)d_in[1];
  const float* bqkv = (const float*)d_in[2];
  const float* Wout = (const float*)d_in[3];
  const float* bout = (const float*)d_in[4];
  float* out = (float*)d_out;

  char* ws = (char*)d_ws;
  short* Xb    = (short*)(ws);                          // 16 MB  [8192,1024] bf16
  short* Wqkvt = (short*)(ws + (16ull << 20));          //  6 MB  [3072,1024] bf16
  short* Woutt = (short*)(ws + (22ull << 20));          //  2 MB  [1024,1024] bf16
  short* Qb    = (short*)(ws + (24ull << 20));          // 16 MB  [64,2048,64] bf16 (pre-scaled)
  short* Kf    = (short*)(ws + (40ull << 20));          // 16 MB  frag-major
  short* Vf    = (short*)(ws + (56ull << 20));          // 16 MB  frag-major
  short* Ao    = (short*)(ws + (72ull << 20));          // 16 MB  [8192,1024] bf16

  cvt_kernel<<<(M_TOK * K_DIM / 4 + 255) / 256, 256, 0, stream>>>(x, Xb, M_TOK * K_DIM);
  dim3 tb(32, 8);
  transpose_cvt<<<dim3(N_QKV / 32, K_DIM / 32), tb, 0, stream>>>(Wqkv, Wqkvt, K_DIM, N_QKV);
  transpose_cvt<<<dim3(DMODEL / 32, K_DIM / 32), tb, 0, stream>>>(Wout, Woutt, K_DIM, DMODEL);

  // gemm0 split: Q+K columns (C^T epilogue) and V columns (normal epilogue)
  gemm_bt<0><<<dim3(M_TOK / 128, 16), 256, 0, stream>>>(
      Xb, Wqkvt, bqkv, Qb, Kf, nullptr, nullptr, M_TOK, N_QKV, K_DIM, 0);
  gemm_bt<1><<<dim3(M_TOK / 128, 8), 256, 0, stream>>>(
      Xb, Wqkvt, bqkv, nullptr, nullptr, Vf, nullptr, M_TOK, N_QKV, K_DIM, 16);

  attn_kernel<<<dim3(64, T_SEQ / 128), 256, 0, stream>>>(Qb, Kf, Vf, Ao);

  gemm_bt<2><<<dim3(M_TOK / 128, DMODEL / 128), 256, 0, stream>>>(
      Ao, Woutt, bout, nullptr, nullptr, nullptr, out, M_TOK, DMODEL, K_DIM, 0);
}